// Round 1
// 633.424 us; speedup vs baseline: 1.4794x; 1.4794x over previous
//
#include <hip/hip_runtime.h>
#include <hip/hip_bf16.h>

// Problem constants
#define NB 8
#define NC 512
#define HW 4096
#define INNER 32

typedef unsigned short u16;
typedef unsigned int u32;

__device__ __forceinline__ float b2f(u16 u) {
    union { u32 a; float f; } z;
    z.a = ((u32)u) << 16;
    return z.f;
}

// Dtype-flexible input load. flag: 1 = fp32 tensors, 0 = bf16 tensors.
// Explicit if/else (NOT ?:) so the compiler cannot speculate the wrong-width
// load out of bounds.
__device__ __forceinline__ float ldin(const void* p, int idx, int isf32) {
    if (isf32) return ((const float*)p)[idx];
    return b2f(((const u16*)p)[idx]);
}

// ---------------------------------------------------------------------------
// Detect tensor dtype from bit patterns of `content`.
// ---------------------------------------------------------------------------
__global__ __launch_bounds__(256) void k_detect(const u16* __restrict__ content,
                                                int* __restrict__ flag) {
    __shared__ int scnt;
    if (threadIdx.x == 0) scnt = 0;
    __syncthreads();
    u16 u = content[threadIdx.x * 2048];
    int e = (u >> 7) & 0xff;
    if (e >= 100 && e <= 150) atomicAdd(&scnt, 1);
    __syncthreads();
    if (threadIdx.x == 0) *flag = (scnt < 128) ? 1 : 0;   // 1 = fp32
}

// ---------------------------------------------------------------------------
// Transpose conv weights [O][J] -> [J][O] fp32
// ---------------------------------------------------------------------------
__global__ __launch_bounds__(256) void k_transpose(const void* __restrict__ src,
        float* __restrict__ dst, int O, int J, const int* __restrict__ flag) {
    int isf32 = *flag;
    int idx = blockIdx.x * 256 + threadIdx.x;
    if (idx >= O * J) return;
    int o = idx / J, j = idx - o * J;
    dst[j * O + o] = ldin(src, idx, isf32);
}

// ---------------------------------------------------------------------------
// Style stats: per (b,c) plane, 9 shifted window sums via inclusion-exclusion.
// ---------------------------------------------------------------------------
__global__ __launch_bounds__(256) void k_style_stats(const void* __restrict__ style,
        float* __restrict__ S, const int* __restrict__ flag) {
    int isf32 = *flag;
    int bc = blockIdx.x;                        // b*512 + c
    int base = bc * HW;
    int tid = threadIdx.x;
    float t = 0.f, top = 0.f, bot = 0.f, lft = 0.f, rgt = 0.f;
    for (int e = tid; e < HW; e += 256) {
        float v = ldin(style, base + e, isf32);
        int h = e >> 6, w = e & 63;
        t += v;
        top += (h == 0)  ? v : 0.f;
        bot += (h == 63) ? v : 0.f;
        lft += (w == 0)  ? v : 0.f;
        rgt += (w == 63) ? v : 0.f;
    }
#pragma unroll
    for (int off = 32; off > 0; off >>= 1) {
        t   += __shfl_down(t, off);
        top += __shfl_down(top, off);
        bot += __shfl_down(bot, off);
        lft += __shfl_down(lft, off);
        rgt += __shfl_down(rgt, off);
    }
    __shared__ float red[4][5];
    int wave = tid >> 6;
    if ((tid & 63) == 0) {
        red[wave][0] = t; red[wave][1] = top; red[wave][2] = bot;
        red[wave][3] = lft; red[wave][4] = rgt;
    }
    __syncthreads();
    if (tid == 0) {
        t   = red[0][0] + red[1][0] + red[2][0] + red[3][0];
        top = red[0][1] + red[1][1] + red[2][1] + red[3][1];
        bot = red[0][2] + red[1][2] + red[2][2] + red[3][2];
        lft = red[0][3] + red[1][3] + red[2][3] + red[3][3];
        rgt = red[0][4] + red[1][4] + red[2][4] + red[3][4];
        float c00 = ldin(style, base + 0,    isf32);
        float c0W = ldin(style, base + 63,   isf32);
        float cH0 = ldin(style, base + 4032, isf32);
        float cHW = ldin(style, base + 4095, isf32);
        float* o = S + bc * 9;
        o[0] = t - bot - rgt + cHW;
        o[1] = t - bot;
        o[2] = t - bot - lft + cH0;
        o[3] = t - rgt;
        o[4] = t;
        o[5] = t - lft;
        o[6] = t - top - rgt + c0W;
        o[7] = t - top;
        o[8] = t - top - lft + c00;
    }
}

// ---------------------------------------------------------------------------
// pooled[set,b,o] = (1/4096)*sum_{c,k} cw[o,c,k]*S[b,c,k] + cb[o]
// ---------------------------------------------------------------------------
__global__ __launch_bounds__(64) void k_pooled(const float* __restrict__ S,
        const void* __restrict__ cw1, const void* __restrict__ cb1,
        const void* __restrict__ cw2, const void* __restrict__ cb2,
        float* __restrict__ pooled, const int* __restrict__ flag) {
    int isf32 = *flag;
    int set = blockIdx.y;
    int b = blockIdx.x >> 5;
    int o = blockIdx.x & 31;
    const void* cw = set ? cw2 : cw1;
    const void* cb = set ? cb2 : cb1;
    int lane = threadIdx.x;
    float acc = 0.f;
    const float* Sb = S + b * NC * 9;
    int wbase = o * NC * 9;
    for (int c = lane; c < NC; c += 64) {
#pragma unroll
        for (int k = 0; k < 9; k++)
            acc += Sb[c * 9 + k] * ldin(cw, wbase + c * 9 + k, isf32);
    }
#pragma unroll
    for (int off = 32; off > 0; off >>= 1) acc += __shfl_down(acc, off);
    if (lane == 0)
        pooled[(set * NB + b) * INNER + o] = acc * (1.0f / 4096.0f) + ldin(cb, o, isf32);
}

// ---------------------------------------------------------------------------
// FC: f[b,row] = pooled[b,:]·fw[row,:] + fb[row]; stored transposed.
// ---------------------------------------------------------------------------
__global__ __launch_bounds__(256) void k_fc(const float* __restrict__ pooled,
        const void* __restrict__ fw1, const void* __restrict__ fb1,
        const void* __restrict__ fw2, const void* __restrict__ fb2,
        float* __restrict__ filtT, const int* __restrict__ flag) {
    int isf32 = *flag;
    int set = blockIdx.y;
    int b = blockIdx.x / 36;
    int chunk = blockIdx.x - b * 36;
    int row = chunk * 256 + threadIdx.x;       // 0..9215
    const void* fw = set ? fw2 : fw1;
    const void* fb = set ? fb2 : fb1;
    __shared__ float p[32];
    if (threadIdx.x < 32) p[threadIdx.x] = pooled[(set * NB + b) * 32 + threadIdx.x];
    __syncthreads();
    float acc = ldin(fb, row, isf32);
    if (isf32) {
        const float* fwf = (const float*)fw + row * 32;
#pragma unroll
        for (int j = 0; j < 32; j++) acc += fwf[j] * p[j];
    } else {
        const u32* w32 = (const u32*)((const u16*)fw + row * 32);
#pragma unroll
        for (int j = 0; j < 16; j++) {
            u32 u = w32[j];
            acc += b2f((u16)(u & 0xffffu)) * p[2 * j];
            acc += b2f((u16)(u >> 16)) * p[2 * j + 1];
        }
    }
    int o = row / 288;
    int rem = row - o * 288;
    filtT[(set * NB + b) * 9216 + rem * 32 + o] = acc;
}

// ---------------------------------------------------------------------------
// Pre-fill c0 with the downsample bias (accumulation target for k_conv_down).
// ---------------------------------------------------------------------------
__global__ __launch_bounds__(256) void k_bias_init(float* __restrict__ c0,
        const void* __restrict__ dsb, const int* __restrict__ flag) {
    int isf32 = *flag;
    int idx = blockIdx.x * 256 + threadIdx.x;  // over NB*32*4096
    int oc = (idx >> 12) & 31;
    c0[idx] = ldin(dsb, oc, isf32);
}

// ---------------------------------------------------------------------------
// Conv 512->32 on content -> c0 (fp32), K-split x4 for occupancy.
// Block = (b,row) x ksplit; each block covers 128 input channels (4 chunks
// of 32 staged in LDS), partial-sums atomically into bias-initialized c0.
// 256 threads = 64 cols x 4 output-groups of 8. wT[(c*9+k)*32+o] fp32.
// ---------------------------------------------------------------------------
__global__ __launch_bounds__(256) void k_conv_down(const void* __restrict__ content,
        const float* __restrict__ wT, float* __restrict__ c0,
        const int* __restrict__ flag) {
    int isf32 = *flag;
    int b = blockIdx.x >> 6, row = blockIdx.x & 63;
    int ks = blockIdx.y;                                // 0..3 channel split
    int tid = threadIdx.x, col = tid & 63;
    int g = __builtin_amdgcn_readfirstlane(tid >> 6);   // 0..3, wave-uniform
    __shared__ float lds[32 * 198];                     // 32 ch x 3 rows x 66 cols
    float acc[8];
#pragma unroll
    for (int o = 0; o < 8; o++) acc[o] = 0.f;
    int cbase = b * NC * HW;

    for (int ci = 0; ci < 4; ci++) {
        int cc = ks * 128 + ci * 32;
        if (ci) __syncthreads();
        for (int idx = tid; idx < 32 * 198; idx += 256) {
            int c = idx / 198;
            int rem = idx - c * 198;
            int r = rem / 66;
            int w = rem - r * 66 - 1;                   // -1..64
            int gh = row + r - 1;
            float v = 0.f;
            if (gh >= 0 && gh < 64 && (unsigned)w < 64u)
                v = ldin(content, cbase + (cc + c) * HW + gh * 64 + w, isf32);
            lds[idx] = v;
        }
        __syncthreads();
        for (int c = 0; c < 32; c++) {
            float x[9];
#pragma unroll
            for (int r = 0; r < 3; r++)
#pragma unroll
                for (int dw = 0; dw < 3; dw++)
                    x[r * 3 + dw] = lds[c * 198 + r * 66 + col + dw];
            const float* wp = wT + (cc + c) * 9 * 32 + g * 8;
#pragma unroll
            for (int k = 0; k < 9; k++) {
                float xv = x[k];
#pragma unroll
                for (int o = 0; o < 8; o++) acc[o] += xv * wp[k * 32 + o];
            }
        }
    }
#pragma unroll
    for (int o = 0; o < 8; o++) {
        int oc = g * 8 + o;
        atomicAdd(&c0[(b * INNER + oc) * HW + row * 64 + col], acc[o]);
    }
}

// ---------------------------------------------------------------------------
// Per-sample dynamic 32->32 conv (+ optional LeakyReLU). fp32 src.
// ---------------------------------------------------------------------------
__global__ __launch_bounds__(256) void k_apply(const float* __restrict__ src,
        const float* __restrict__ filtT, void* __restrict__ dst,
        int lrelu, int dstBf16) {
    int b = blockIdx.x >> 6, row = blockIdx.x & 63;
    int tid = threadIdx.x, col = tid & 63;
    int g = __builtin_amdgcn_readfirstlane(tid >> 6);
    __shared__ float lds[32 * 198];
    const float* sp = src + b * INNER * HW;
    for (int idx = tid; idx < 32 * 198; idx += 256) {
        int c = idx / 198;
        int rem = idx - c * 198;
        int r = rem / 66;
        int w = rem - r * 66 - 1;
        int gh = row + r - 1;
        float v = 0.f;
        if (gh >= 0 && gh < 64 && (unsigned)w < 64u)
            v = sp[c * HW + gh * 64 + w];
        lds[idx] = v;
    }
    __syncthreads();
    float acc[8];
#pragma unroll
    for (int o = 0; o < 8; o++) acc[o] = 0.f;
    const float* fbp = filtT + b * 9216 + g * 8;
    for (int c = 0; c < 32; c++) {
        float x[9];
#pragma unroll
        for (int r = 0; r < 3; r++)
#pragma unroll
            for (int dw = 0; dw < 3; dw++)
                x[r * 3 + dw] = lds[c * 198 + r * 66 + col + dw];
        const float* wp = fbp + c * 288;
#pragma unroll
        for (int k = 0; k < 9; k++) {
            float xv = x[k];
#pragma unroll
            for (int o = 0; o < 8; o++) acc[o] += xv * wp[k * 32 + o];
        }
    }
#pragma unroll
    for (int o = 0; o < 8; o++) {
        float v = acc[o];
        if (lrelu) v = (v >= 0.f) ? v : 0.2f * v;
        int di = (b * INNER + g * 8 + o) * HW + row * 64 + col;
        if (dstBf16) ((__hip_bfloat16*)dst)[di] = __float2bfloat16(v);
        else         ((float*)dst)[di] = v;
    }
}

// ---------------------------------------------------------------------------
// Conv 32->512 (+bias) + residual content -> out (dtype per flag).
// c2 is bf16. Block = (b,row) x pass; each block stages the 32-channel c2
// window once and computes 64 output channels (pass = blockIdx.y).
// ---------------------------------------------------------------------------
__global__ __launch_bounds__(256) void k_conv_up(const u16* __restrict__ c2,
        const float* __restrict__ wT, const void* __restrict__ upb,
        const void* __restrict__ content, void* __restrict__ outv,
        const int* __restrict__ flag) {
    int isf32 = *flag;
    int b = blockIdx.x >> 6, row = blockIdx.x & 63;
    int pass = blockIdx.y;                              // 0..7
    int tid = threadIdx.x, col = tid & 63;
    int g = __builtin_amdgcn_readfirstlane(tid >> 6);   // 0..3
    __shared__ float lds[32 * 198];
    const u16* sp = c2 + b * INNER * HW;
    for (int idx = tid; idx < 32 * 198; idx += 256) {
        int c = idx / 198;
        int rem = idx - c * 198;
        int r = rem / 66;
        int w = rem - r * 66 - 1;
        int gh = row + r - 1;
        float v = 0.f;
        if (gh >= 0 && gh < 64 && (unsigned)w < 64u)
            v = b2f(sp[c * HW + gh * 64 + w]);
        lds[idx] = v;
    }
    __syncthreads();

    float acc[16];
#pragma unroll
    for (int o = 0; o < 16; o++) acc[o] = 0.f;
    for (int c = 0; c < 32; c++) {
        float x[9];
#pragma unroll
        for (int r = 0; r < 3; r++)
#pragma unroll
            for (int dw = 0; dw < 3; dw++)
                x[r * 3 + dw] = lds[c * 198 + r * 66 + col + dw];
        const float* wp = wT + c * 9 * 512 + pass * 64 + g * 16;
#pragma unroll
        for (int k = 0; k < 9; k++) {
            float xv = x[k];
#pragma unroll
            for (int o = 0; o < 16; o++) acc[o] += xv * wp[k * 512 + o];
        }
    }
#pragma unroll
    for (int o = 0; o < 16; o++) {
        int oc = pass * 64 + g * 16 + o;
        int idx = (b * NC + oc) * HW + row * 64 + col;
        float v = acc[o] + ldin(upb, oc, isf32) + ldin(content, idx, isf32);
        if (isf32) ((float*)outv)[idx] = v;
        else       ((__hip_bfloat16*)outv)[idx] = __float2bfloat16(v);
    }
}

// ---------------------------------------------------------------------------
extern "C" void kernel_launch(void* const* d_in, const int* in_sizes, int n_in,
                              void* d_out, int out_size, void* d_ws, size_t ws_size,
                              hipStream_t stream) {
    const void* content = d_in[0];
    const void* style   = d_in[1];
    const void* ds_w    = d_in[2];
    const void* ds_b    = d_in[3];
    const void* up_w    = d_in[4];
    const void* up_b    = d_in[5];
    const void* f1_cw   = d_in[6];
    const void* f1_cb   = d_in[7];
    const void* f1_fw   = d_in[8];
    const void* f1_fb   = d_in[9];
    const void* f2_cw   = d_in[10];
    const void* f2_cb   = d_in[11];
    const void* f2_fw   = d_in[12];
    const void* f2_fb   = d_in[13];

    // d_out doubles as scratch for everything DEAD before the final kernel.
    // Worst-case capacity (bf16 out): 16,777,216*2 B = 8,388,608 floats.
    // Used: 2,429,440 floats. The final kernel reads NOTHING from d_out.
    float* dscr   = (float*)d_out;
    float* c0     = dscr;                  // 1,048,576
    float* c1     = c0 + 1048576;          // 1,048,576
    float* wTds   = c1 + 1048576;          //   147,456
    float* S      = wTds + 147456;         //    36,864
    float* pooled = S + 36864;             //       512
    float* filtT  = pooled + 512;          //   147,456 (both sets)

    // d_ws holds ONLY what the final kernel reads: 2,687,008 bytes total.
    int*   flag = (int*)d_ws;
    float* wTup = (float*)((char*)d_ws + 16);        // 147,456 fp32
    u16*   c2   = (u16*)(wTup + 147456);             // 1,048,576 bf16

    k_detect<<<1, 256, 0, stream>>>((const u16*)content, flag);
    k_transpose<<<576, 256, 0, stream>>>(ds_w, wTds, 32, 4608, flag);
    k_transpose<<<576, 256, 0, stream>>>(up_w, wTup, 512, 288, flag);
    k_style_stats<<<NB * NC, 256, 0, stream>>>(style, S, flag);
    k_pooled<<<dim3(NB * 32, 2), 64, 0, stream>>>(S, f1_cw, f1_cb, f2_cw, f2_cb, pooled, flag);
    k_fc<<<dim3(NB * 36, 2), 256, 0, stream>>>(pooled, f1_fw, f1_fb, f2_fw, f2_fb, filtT, flag);
    k_bias_init<<<4096, 256, 0, stream>>>(c0, ds_b, flag);
    k_conv_down<<<dim3(NB * 64, 4), 256, 0, stream>>>(content, wTds, c0, flag);
    k_apply<<<NB * 64, 256, 0, stream>>>(c0, filtT, c1, 1, 0);
    k_apply<<<NB * 64, 256, 0, stream>>>(c1, filtT + NB * 9216, c2, 0, 1);
    k_conv_up<<<dim3(NB * 64, 8), 256, 0, stream>>>(c2, wTup, up_b, content, d_out, flag);
}

// Round 2
// 369.939 us; speedup vs baseline: 2.5330x; 1.7122x over previous
//
#include <hip/hip_runtime.h>
#include <hip/hip_bf16.h>

// Problem constants
#define NB 8
#define NC 512
#define HW 4096
#define INNER 32

typedef unsigned short u16;
typedef unsigned int u32;
typedef __attribute__((ext_vector_type(8))) short bf16x8;   // 8 bf16 = 4 VGPRs
typedef __attribute__((ext_vector_type(4))) float f32x4;    // MFMA C/D

__device__ __forceinline__ float b2f(u16 u) {
    union { u32 a; float f; } z;
    z.a = ((u32)u) << 16;
    return z.f;
}

// fp32 -> bf16 with round-to-nearest-even
__device__ __forceinline__ u16 f2b(float v) {
    u32 x = __float_as_uint(v);
    return (u16)((x + 0x7fffu + ((x >> 16) & 1u)) >> 16);
}

// Dtype-flexible input load. flag: 1 = fp32 tensors, 0 = bf16 tensors.
__device__ __forceinline__ float ldin(const void* p, int idx, int isf32) {
    if (isf32) return ((const float*)p)[idx];
    return b2f(((const u16*)p)[idx]);
}

// async global->LDS, 16 B per lane, dest = wave-uniform base + lane*16
__device__ __forceinline__ void gld_lds16(const void* g, void* l) {
    __builtin_amdgcn_global_load_lds(
        (const __attribute__((address_space(1))) unsigned int*)g,
        (__attribute__((address_space(3))) unsigned int*)l, 16, 0, 0);
}

// ---------------------------------------------------------------------------
// Detect tensor dtype from bit patterns of `content`.
// ---------------------------------------------------------------------------
__global__ __launch_bounds__(256) void k_detect(const u16* __restrict__ content,
                                                int* __restrict__ flag) {
    __shared__ int scnt;
    if (threadIdx.x == 0) scnt = 0;
    __syncthreads();
    u16 u = content[threadIdx.x * 2048];
    int e = (u >> 7) & 0xff;
    if (e >= 100 && e <= 150) atomicAdd(&scnt, 1);
    __syncthreads();
    if (threadIdx.x == 0) *flag = (scnt < 128) ? 1 : 0;   // 1 = fp32
}

// ---------------------------------------------------------------------------
// Pack ds_w [32][512][3][3] -> MFMA B-fragments (bf16).
// B_pack elem idx = (((t*16 + cb)*2 + nf)*64 + lane)*8 + e
//   oc = nf*16 + (lane&15), c = cb*32 + (lane>>4)*8 + e  (k-map f shared w/ A)
// ---------------------------------------------------------------------------
__global__ __launch_bounds__(256) void k_prep_wdown(const void* __restrict__ dsw,
        u16* __restrict__ Bp, const int* __restrict__ flag) {
    int isf32 = *flag;
    int idx = blockIdx.x * 256 + threadIdx.x;       // < 147456
    int e = idx & 7, l = (idx >> 3) & 63, nf = (idx >> 9) & 1;
    int cb = (idx >> 10) & 15, t9 = idx >> 14;
    int oc = nf * 16 + (l & 15);
    int c = cb * 32 + (l >> 4) * 8 + e;
    Bp[idx] = f2b(ldin(dsw, (oc * NC + c) * 9 + t9, isf32));
}

// ---------------------------------------------------------------------------
// Pack up_w [512][32][3][3] -> B2_pack, elem idx = ((t*32 + nfo)*64 + lane)*8 + e
//   oc = nfo*16 + (lane&15), ic = (lane>>4)*8 + e
// ---------------------------------------------------------------------------
__global__ __launch_bounds__(256) void k_prep_wup(const void* __restrict__ upw,
        u16* __restrict__ B2p, const int* __restrict__ flag) {
    int isf32 = *flag;
    int idx = blockIdx.x * 256 + threadIdx.x;       // < 147456
    int e = idx & 7, l = (idx >> 3) & 63, nfo = (idx >> 9) & 31, t9 = idx >> 14;
    int oc = nfo * 16 + (l & 15);
    int ic = (l >> 4) * 8 + e;
    B2p[idx] = f2b(ldin(upw, (oc * INNER + ic) * 9 + t9, isf32));
}

// ---------------------------------------------------------------------------
// Style stats: per (b,c) plane, 9 shifted window sums via inclusion-exclusion.
// ---------------------------------------------------------------------------
__global__ __launch_bounds__(256) void k_style_stats(const void* __restrict__ style,
        float* __restrict__ S, const int* __restrict__ flag) {
    int isf32 = *flag;
    int bc = blockIdx.x;                        // b*512 + c
    int base = bc * HW;
    int tid = threadIdx.x;
    float t = 0.f, top = 0.f, bot = 0.f, lft = 0.f, rgt = 0.f;
    for (int e = tid; e < HW; e += 256) {
        float v = ldin(style, base + e, isf32);
        int h = e >> 6, w = e & 63;
        t += v;
        top += (h == 0)  ? v : 0.f;
        bot += (h == 63) ? v : 0.f;
        lft += (w == 0)  ? v : 0.f;
        rgt += (w == 63) ? v : 0.f;
    }
#pragma unroll
    for (int off = 32; off > 0; off >>= 1) {
        t   += __shfl_down(t, off);
        top += __shfl_down(top, off);
        bot += __shfl_down(bot, off);
        lft += __shfl_down(lft, off);
        rgt += __shfl_down(rgt, off);
    }
    __shared__ float red[4][5];
    int wave = tid >> 6;
    if ((tid & 63) == 0) {
        red[wave][0] = t; red[wave][1] = top; red[wave][2] = bot;
        red[wave][3] = lft; red[wave][4] = rgt;
    }
    __syncthreads();
    if (tid == 0) {
        t   = red[0][0] + red[1][0] + red[2][0] + red[3][0];
        top = red[0][1] + red[1][1] + red[2][1] + red[3][1];
        bot = red[0][2] + red[1][2] + red[2][2] + red[3][2];
        lft = red[0][3] + red[1][3] + red[2][3] + red[3][3];
        rgt = red[0][4] + red[1][4] + red[2][4] + red[3][4];
        float c00 = ldin(style, base + 0,    isf32);
        float c0W = ldin(style, base + 63,   isf32);
        float cH0 = ldin(style, base + 4032, isf32);
        float cHW = ldin(style, base + 4095, isf32);
        float* o = S + bc * 9;
        o[0] = t - bot - rgt + cHW;
        o[1] = t - bot;
        o[2] = t - bot - lft + cH0;
        o[3] = t - rgt;
        o[4] = t;
        o[5] = t - lft;
        o[6] = t - top - rgt + c0W;
        o[7] = t - top;
        o[8] = t - top - lft + c00;
    }
}

// ---------------------------------------------------------------------------
// pooled[set,b,o] = (1/4096)*sum_{c,k} cw[o,c,k]*S[b,c,k] + cb[o]
// ---------------------------------------------------------------------------
__global__ __launch_bounds__(64) void k_pooled(const float* __restrict__ S,
        const void* __restrict__ cw1, const void* __restrict__ cb1,
        const void* __restrict__ cw2, const void* __restrict__ cb2,
        float* __restrict__ pooled, const int* __restrict__ flag) {
    int isf32 = *flag;
    int set = blockIdx.y;
    int b = blockIdx.x >> 5;
    int o = blockIdx.x & 31;
    const void* cw = set ? cw2 : cw1;
    const void* cb = set ? cb2 : cb1;
    int lane = threadIdx.x;
    float acc = 0.f;
    const float* Sb = S + b * NC * 9;
    int wbase = o * NC * 9;
    for (int c = lane; c < NC; c += 64) {
#pragma unroll
        for (int k = 0; k < 9; k++)
            acc += Sb[c * 9 + k] * ldin(cw, wbase + c * 9 + k, isf32);
    }
#pragma unroll
    for (int off = 32; off > 0; off >>= 1) acc += __shfl_down(acc, off);
    if (lane == 0)
        pooled[(set * NB + b) * INNER + o] = acc * (1.0f / 4096.0f) + ldin(cb, o, isf32);
}

// ---------------------------------------------------------------------------
// FC: f[b,row] = pooled[b,:]·fw[row,:] + fb[row]; written as bf16 MFMA
// B-fragments: fpack[(((bb*9 + t)*2 + nf)*64 + l)*8 + e], bb = set*8+b,
//   oc = nf*16+(l&15), ic = (l>>4)*8+e,  row = oc*288 + ic*9 + t.
// ---------------------------------------------------------------------------
__global__ __launch_bounds__(256) void k_fc(const float* __restrict__ pooled,
        const void* __restrict__ fw1, const void* __restrict__ fb1,
        const void* __restrict__ fw2, const void* __restrict__ fb2,
        u16* __restrict__ fpack, const int* __restrict__ flag) {
    int isf32 = *flag;
    int set = blockIdx.y;
    int b = blockIdx.x / 36;
    int chunk = blockIdx.x - b * 36;
    int row = chunk * 256 + threadIdx.x;       // 0..9215
    const void* fw = set ? fw2 : fw1;
    const void* fb = set ? fb2 : fb1;
    __shared__ float p[32];
    if (threadIdx.x < 32) p[threadIdx.x] = pooled[(set * NB + b) * 32 + threadIdx.x];
    __syncthreads();
    float acc = ldin(fb, row, isf32);
    if (isf32) {
        const float* fwf = (const float*)fw + row * 32;
#pragma unroll
        for (int j = 0; j < 32; j++) acc += fwf[j] * p[j];
    } else {
        const u32* w32 = (const u32*)((const u16*)fw + row * 32);
#pragma unroll
        for (int j = 0; j < 16; j++) {
            u32 u = w32[j];
            acc += b2f((u16)(u & 0xffffu)) * p[2 * j];
            acc += b2f((u16)(u >> 16)) * p[2 * j + 1];
        }
    }
    int oc = row / 288;
    int rem = row - oc * 288;
    int ic = rem / 9;
    int t9 = rem - ic * 9;
    int l = (oc & 15) | ((ic >> 3) << 4);
    int e = ic & 7;
    int nf = oc >> 4;
    fpack[((((set * NB + b) * 9 + t9) * 2 + nf) * 64 + l) * 8 + e] = f2b(acc);
}

// ---------------------------------------------------------------------------
// Conv 512->32 (MFMA implicit GEMM). One block per (b,row). 4 waves, each
// owns a 16-pixel M-tile x 32 oc. 16 chunks of 32 input channels.
// LDS [3][66][32] bf16, c-blocks XOR-swizzled by (wi&3) to kill the
// transpose-write bank conflict; A-frag reads apply the same XOR.
// Output: c0T[b][h][w][oc] bf16 (+bias).
// ---------------------------------------------------------------------------
__global__ __launch_bounds__(256) void k_conv_down(const void* __restrict__ content,
        const u16* __restrict__ Bp, const void* __restrict__ dsb,
        u16* __restrict__ c0T, const int* __restrict__ flag) {
    int isf32 = *flag;
    int b = blockIdx.x >> 6, row = blockIdx.x & 63;
    int tid = threadIdx.x, lane = tid & 63;
    int wid = __builtin_amdgcn_readfirstlane(tid >> 6);
    __shared__ u16 lds[3 * 66 * 32];
    u32* lds32 = (u32*)lds;

    // zero halo columns wi=0 and wi=65 (never written by staging)
    for (int i = tid; i < 96; i += 256) {
        int r = i >> 5, side = (i >> 4) & 1, cpr = i & 15;
        lds32[(r * 66 + side * 65) * 16 + cpr] = 0u;
    }

    int cp  = tid & 15;           // c-pair 0..15 -> channels 2cp, 2cp+1
    int c2i = cp * 2;
    int seg = tid >> 4;           // 0..15 (w-segment, strided for bank spread)
    int m   = lane & 15;
    int g   = lane >> 4;
    int wbase = wid * 16;
    long cbase = (long)b * NC * HW;

    f32x4 acc0 = {0.f, 0.f, 0.f, 0.f}, acc1 = {0.f, 0.f, 0.f, 0.f};
    int cb2w = (c2i >> 3);        // c-block of this thread's pair

    for (int ci = 0; ci < 16; ci++) {
        int cc = ci * 32;
        if (ci) __syncthreads();
        // stage: transpose [c][w] -> [wi][c'] bf16 with XOR swizzle
        for (int r = 0; r < 3; r++) {
            int gh = row + r - 1;
            bool valid = (gh >= 0) && (gh < 64);
            long gb = cbase + (long)(cc + c2i) * HW + gh * 64;
#pragma unroll
            for (int j = 0; j < 4; j++) {
                int w = seg + j * 16;
                float v0 = 0.f, v1 = 0.f;
                if (valid) {
                    v0 = ldin(content, gb + w, isf32);
                    v1 = ldin(content, gb + HW + w, isf32);
                }
                u32 pk = (u32)f2b(v0) | ((u32)f2b(v1) << 16);
                int wi = w + 1;
                int cpr = ((c2i & 7) | (((cb2w ^ (wi & 3))) << 3)) >> 1;
                lds32[(r * 66 + wi) * 16 + cpr] = pk;
            }
        }
        __syncthreads();
        // compute: 9 taps x 2 N-frags
#pragma unroll
        for (int t9 = 0; t9 < 9; t9++) {
            int dh = t9 / 3, dw = t9 - dh * 3;
            int wi = wbase + m + dw;
            int cg = g ^ (wi & 3);
            bf16x8 a = *(const bf16x8*)(lds + ((dh * 66 + wi) * 32 + cg * 8));
            bf16x8 b0 = ((const bf16x8*)Bp)[((t9 * 16 + ci) * 2 + 0) * 64 + lane];
            bf16x8 b1 = ((const bf16x8*)Bp)[((t9 * 16 + ci) * 2 + 1) * 64 + lane];
            acc0 = __builtin_amdgcn_mfma_f32_16x16x32_bf16(a, b0, acc0, 0, 0, 0);
            acc1 = __builtin_amdgcn_mfma_f32_16x16x32_bf16(a, b1, acc1, 0, 0, 0);
        }
    }
    // epilogue: D col=lane&15 -> oc, row=(lane>>4)*4+r -> pixel
    float bia0 = ldin(dsb, m, isf32);
    float bia1 = ldin(dsb, 16 + m, isf32);
    size_t obase = ((size_t)(b * 64 + row) * 64) * 32;
    int pix0 = wbase + g * 4;
#pragma unroll
    for (int r = 0; r < 4; r++) {
        c0T[obase + (size_t)(pix0 + r) * 32 + m]      = f2b(acc0[r] + bia0);
        c0T[obase + (size_t)(pix0 + r) * 32 + 16 + m] = f2b(acc1[r] + bia1);
    }
}

// ---------------------------------------------------------------------------
// Per-sample dynamic 32->32 conv (MFMA) + optional LeakyReLU.
// srcT/dstT: [b][h][w][c] bf16. Staged via global_load_lds (linear layout).
// ---------------------------------------------------------------------------
__global__ __launch_bounds__(256) void k_apply(const u16* __restrict__ srcT,
        const u16* __restrict__ fpack, u16* __restrict__ dstT, int lrelu) {
    int b = blockIdx.x >> 6, row = blockIdx.x & 63;
    int tid = threadIdx.x, lane = tid & 63;
    int wid = __builtin_amdgcn_readfirstlane(tid >> 6);
    __shared__ u16 lds[3 * 66 * 32];
    u32* lds32 = (u32*)lds;
    for (int i = tid; i < 96; i += 256) {
        int r = i >> 5, side = (i >> 4) & 1, cpr = i & 15;
        lds32[(r * 66 + side * 65) * 16 + cpr] = 0u;
    }
    const u16* sp = srcT + (size_t)b * 64 * 64 * 32;
    for (int r = 0; r < 3; r++) {
        int gh = row + r - 1;
        u32 ldsoff = (u32)(r * 66 + 1) * 64 + (u32)wid * 1024;  // bytes
        if (gh >= 0 && gh < 64) {
            int j = wid * 64 + lane;
            int w = j >> 2, co = (j & 3) * 8;
            gld_lds16(sp + ((size_t)gh * 64 + w) * 32 + co, (char*)lds + ldsoff);
        } else {
            int4 z = make_int4(0, 0, 0, 0);
            *(int4*)((char*)lds + ldsoff + (u32)lane * 16) = z;
        }
    }
    __syncthreads();

    int m = lane & 15, g = lane >> 4, wbase = wid * 16;
    f32x4 acc0 = {0.f, 0.f, 0.f, 0.f}, acc1 = {0.f, 0.f, 0.f, 0.f};
    const bf16x8* FB = (const bf16x8*)fpack + (size_t)b * 1152;
#pragma unroll
    for (int t9 = 0; t9 < 9; t9++) {
        int dh = t9 / 3, dw = t9 - dh * 3;
        int wi = wbase + m + dw;
        bf16x8 a = *(const bf16x8*)(lds + ((dh * 66 + wi) * 32 + g * 8));
        bf16x8 b0 = FB[(t9 * 2 + 0) * 64 + lane];
        bf16x8 b1 = FB[(t9 * 2 + 1) * 64 + lane];
        acc0 = __builtin_amdgcn_mfma_f32_16x16x32_bf16(a, b0, acc0, 0, 0, 0);
        acc1 = __builtin_amdgcn_mfma_f32_16x16x32_bf16(a, b1, acc1, 0, 0, 0);
    }
    size_t obase = ((size_t)(b * 64 + row) * 64) * 32;
    int pix0 = wbase + g * 4;
#pragma unroll
    for (int r = 0; r < 4; r++) {
        float v0 = acc0[r], v1 = acc1[r];
        if (lrelu) {
            v0 = (v0 >= 0.f) ? v0 : 0.2f * v0;
            v1 = (v1 >= 0.f) ? v1 : 0.2f * v1;
        }
        dstT[obase + (size_t)(pix0 + r) * 32 + m]      = f2b(v0);
        dstT[obase + (size_t)(pix0 + r) * 32 + 16 + m] = f2b(v1);
    }
}

// ---------------------------------------------------------------------------
// Conv 32->512 (MFMA) + bias + residual content -> out (dtype per flag).
// blockIdx.y = quarter of output channels (128 oc = 8 N-frags).
// ---------------------------------------------------------------------------
__global__ __launch_bounds__(256) void k_conv_up(const u16* __restrict__ c2T,
        const u16* __restrict__ B2p, const void* __restrict__ upb,
        const void* __restrict__ content, void* __restrict__ outv,
        const int* __restrict__ flag) {
    int isf32 = *flag;
    int b = blockIdx.x >> 6, row = blockIdx.x & 63;
    int nq = blockIdx.y;                           // 0..3
    int tid = threadIdx.x, lane = tid & 63;
    int wid = __builtin_amdgcn_readfirstlane(tid >> 6);
    __shared__ u16 lds[3 * 66 * 32];
    u32* lds32 = (u32*)lds;
    for (int i = tid; i < 96; i += 256) {
        int r = i >> 5, side = (i >> 4) & 1, cpr = i & 15;
        lds32[(r * 66 + side * 65) * 16 + cpr] = 0u;
    }
    const u16* sp = c2T + (size_t)b * 64 * 64 * 32;
    for (int r = 0; r < 3; r++) {
        int gh = row + r - 1;
        u32 ldsoff = (u32)(r * 66 + 1) * 64 + (u32)wid * 1024;
        if (gh >= 0 && gh < 64) {
            int j = wid * 64 + lane;
            int w = j >> 2, co = (j & 3) * 8;
            gld_lds16(sp + ((size_t)gh * 64 + w) * 32 + co, (char*)lds + ldsoff);
        } else {
            int4 z = make_int4(0, 0, 0, 0);
            *(int4*)((char*)lds + ldsoff + (u32)lane * 16) = z;
        }
    }
    __syncthreads();

    int m = lane & 15, g = lane >> 4, wbase = wid * 16;
    f32x4 acc[8];
#pragma unroll
    for (int i = 0; i < 8; i++) acc[i] = (f32x4){0.f, 0.f, 0.f, 0.f};
#pragma unroll
    for (int t9 = 0; t9 < 9; t9++) {
        int dh = t9 / 3, dw = t9 - dh * 3;
        int wi = wbase + m + dw;
        bf16x8 a = *(const bf16x8*)(lds + ((dh * 66 + wi) * 32 + g * 8));
#pragma unroll
        for (int nfl = 0; nfl < 8; nfl++) {
            bf16x8 bw = ((const bf16x8*)B2p)[(t9 * 32 + nq * 8 + nfl) * 64 + lane];
            acc[nfl] = __builtin_amdgcn_mfma_f32_16x16x32_bf16(a, bw, acc[nfl], 0, 0, 0);
        }
    }
    int pix0 = wbase + g * 4;
#pragma unroll
    for (int nfl = 0; nfl < 8; nfl++) {
        int oc = nq * 128 + nfl * 16 + m;
        size_t idx = ((size_t)b * NC + oc) * HW + (size_t)row * 64 + pix0;
        float bias = ldin(upb, oc, isf32);
        if (isf32) {
            f32x4 rsd = *(const f32x4*)((const float*)content + idx);
            f32x4 v;
#pragma unroll
            for (int r = 0; r < 4; r++) v[r] = acc[nfl][r] + bias + rsd[r];
            *(f32x4*)((float*)outv + idx) = v;
        } else {
#pragma unroll
            for (int r = 0; r < 4; r++) {
                float rv = b2f(((const u16*)content)[idx + r]);
                ((u16*)outv)[idx + r] = f2b(acc[nfl][r] + bias + rv);
            }
        }
    }
}

// ---------------------------------------------------------------------------
extern "C" void kernel_launch(void* const* d_in, const int* in_sizes, int n_in,
                              void* d_out, int out_size, void* d_ws, size_t ws_size,
                              hipStream_t stream) {
    const void* content = d_in[0];
    const void* style   = d_in[1];
    const void* ds_w    = d_in[2];
    const void* ds_b    = d_in[3];
    const void* up_w    = d_in[4];
    const void* up_b    = d_in[5];
    const void* f1_cw   = d_in[6];
    const void* f1_cb   = d_in[7];
    const void* f1_fw   = d_in[8];
    const void* f1_fb   = d_in[9];
    const void* f2_cw   = d_in[10];
    const void* f2_cb   = d_in[11];
    const void* f2_fw   = d_in[12];
    const void* f2_fb   = d_in[13];

    // d_out doubles as scratch for everything DEAD before the final kernel.
    // Worst-case capacity (bf16 out): 8,388,608 f32. Used: ~1.24M f32.
    // The final kernel (k_conv_up) reads NOTHING from d_out.
    float* S      = (float*)d_out;               //    36,864 f32
    float* pooled = S + 36864;                   //       512 f32
    u16*   fpack  = (u16*)(pooled + 512);        //   147,456 u16 (both sets)
    u16*   Bpack  = fpack + 147456;              //   147,456 u16
    u16*   c0T    = Bpack + 147456;              // 1,048,576 u16
    u16*   c1T    = c0T + 1048576;               // 1,048,576 u16

    // d_ws holds ONLY what the final kernel reads: 2,392,080 bytes.
    int*   flag   = (int*)d_ws;
    u16*   B2pack = (u16*)((char*)d_ws + 16);    //   147,456 u16
    u16*   c2T    = B2pack + 147456;             // 1,048,576 u16

    k_detect<<<1, 256, 0, stream>>>((const u16*)content, flag);
    k_prep_wdown<<<576, 256, 0, stream>>>(ds_w, Bpack, flag);
    k_prep_wup<<<576, 256, 0, stream>>>(up_w, B2pack, flag);
    k_style_stats<<<NB * NC, 256, 0, stream>>>(style, S, flag);
    k_pooled<<<dim3(NB * 32, 2), 64, 0, stream>>>(S, f1_cw, f1_cb, f2_cw, f2_cb, pooled, flag);
    k_fc<<<dim3(NB * 36, 2), 256, 0, stream>>>(pooled, f1_fw, f1_fb, f2_fw, f2_fb, fpack, flag);
    k_conv_down<<<NB * 64, 256, 0, stream>>>(content, Bpack, ds_b, c0T, flag);
    k_apply<<<NB * 64, 256, 0, stream>>>(c0T, fpack, c1T, 1);
    k_apply<<<NB * 64, 256, 0, stream>>>(c1T, fpack + NB * 9216, c2T, 0);
    k_conv_up<<<dim3(NB * 64, 4), 256, 0, stream>>>(c2T, B2pack, up_b, content, d_out, flag);
}

// Round 3
// 330.895 us; speedup vs baseline: 2.8319x; 1.1180x over previous
//
#include <hip/hip_runtime.h>
#include <hip/hip_bf16.h>

// Problem constants
#define NB 8
#define NC 512
#define HW 4096
#define INNER 32

typedef unsigned short u16;
typedef unsigned int u32;
typedef __attribute__((ext_vector_type(8))) short bf16x8;   // 8 bf16 = 4 VGPRs
typedef __attribute__((ext_vector_type(4))) float f32x4;    // MFMA C/D

__device__ __forceinline__ float b2f(u16 u) {
    union { u32 a; float f; } z;
    z.a = ((u32)u) << 16;
    return z.f;
}

// fp32 -> bf16 with round-to-nearest-even
__device__ __forceinline__ u16 f2b(float v) {
    u32 x = __float_as_uint(v);
    return (u16)((x + 0x7fffu + ((x >> 16) & 1u)) >> 16);
}

// Dtype-flexible input load. flag: 1 = fp32 tensors, 0 = bf16 tensors.
__device__ __forceinline__ float ldin(const void* p, int idx, int isf32) {
    if (isf32) return ((const float*)p)[idx];
    return b2f(((const u16*)p)[idx]);
}

// async global->LDS, 16 B per lane, dest = wave-uniform base + lane*16
__device__ __forceinline__ void gld_lds16(const void* g, void* l) {
    __builtin_amdgcn_global_load_lds(
        (const __attribute__((address_space(1))) unsigned int*)g,
        (__attribute__((address_space(3))) unsigned int*)l, 16, 0, 0);
}

// ---------------------------------------------------------------------------
// Detect tensor dtype from bit patterns of `content`.
// ---------------------------------------------------------------------------
__global__ __launch_bounds__(256) void k_detect(const u16* __restrict__ content,
                                                int* __restrict__ flag) {
    __shared__ int scnt;
    if (threadIdx.x == 0) scnt = 0;
    __syncthreads();
    u16 u = content[threadIdx.x * 2048];
    int e = (u >> 7) & 0xff;
    if (e >= 100 && e <= 150) atomicAdd(&scnt, 1);
    __syncthreads();
    if (threadIdx.x == 0) *flag = (scnt < 128) ? 1 : 0;   // 1 = fp32
}

// ---------------------------------------------------------------------------
// Pack ds_w [32][512][3][3] -> MFMA B-fragments (bf16).
// B_pack elem idx = (((t*16 + cb)*2 + nf)*64 + lane)*8 + e
//   oc = nf*16 + (lane&15), c = cb*32 + (lane>>4)*8 + e  (k-map f shared w/ A)
// ---------------------------------------------------------------------------
__global__ __launch_bounds__(256) void k_prep_wdown(const void* __restrict__ dsw,
        u16* __restrict__ Bp, const int* __restrict__ flag) {
    int isf32 = *flag;
    int idx = blockIdx.x * 256 + threadIdx.x;       // < 147456
    int e = idx & 7, l = (idx >> 3) & 63, nf = (idx >> 9) & 1;
    int cb = (idx >> 10) & 15, t9 = idx >> 14;
    int oc = nf * 16 + (l & 15);
    int c = cb * 32 + (l >> 4) * 8 + e;
    Bp[idx] = f2b(ldin(dsw, (oc * NC + c) * 9 + t9, isf32));
}

// ---------------------------------------------------------------------------
// Pack up_w [512][32][3][3] -> B2_pack, elem idx = ((t*32 + nfo)*64 + lane)*8 + e
//   oc = nfo*16 + (lane&15), ic = (lane>>4)*8 + e
// ---------------------------------------------------------------------------
__global__ __launch_bounds__(256) void k_prep_wup(const void* __restrict__ upw,
        u16* __restrict__ B2p, const int* __restrict__ flag) {
    int isf32 = *flag;
    int idx = blockIdx.x * 256 + threadIdx.x;       // < 147456
    int e = idx & 7, l = (idx >> 3) & 63, nfo = (idx >> 9) & 31, t9 = idx >> 14;
    int oc = nfo * 16 + (l & 15);
    int ic = (l >> 4) * 8 + e;
    B2p[idx] = f2b(ldin(upw, (oc * INNER + ic) * 9 + t9, isf32));
}

// ---------------------------------------------------------------------------
// Transpose content [b][c][h][w] (f32/bf16) -> cT [(b4*16+ci)][h][w][32] bf16,
// with the c-group XOR swizzle baked in: physical slot p holds logical channel
// lc(p) = ((p>>3) ^ ((w+1)&3))*8 + (p&7).  One block per (b4, ci, h).
// Reads coalesced along w; writes fully contiguous u32s.
// ---------------------------------------------------------------------------
__global__ __launch_bounds__(256) void k_transform(const void* __restrict__ content,
        u16* __restrict__ cT, int bstart, const int* __restrict__ flag) {
    int isf32 = *flag;
    int h  = blockIdx.x & 63;
    int ci = (blockIdx.x >> 6) & 15;
    int b4 = blockIdx.x >> 10;          // 0..3
    int tid = threadIdx.x;
    __shared__ float lds[32 * 65];      // padded rows: bank-spread transpose read
    size_t gbase = ((size_t)(bstart + b4) * NC + ci * 32) * HW + (size_t)h * 64;
    if (isf32) {
#pragma unroll
        for (int k = 0; k < 2; k++) {
            int q = tid + k * 256;                  // 0..511 float4s
            int c = q >> 4, w0 = (q & 15) * 4;
            float4 v = *(const float4*)((const float*)content + gbase + (size_t)c * HW + w0);
            lds[c * 65 + w0 + 0] = v.x;
            lds[c * 65 + w0 + 1] = v.y;
            lds[c * 65 + w0 + 2] = v.z;
            lds[c * 65 + w0 + 3] = v.w;
        }
    } else {
        int c = tid >> 3, w0 = (tid & 7) * 8;
        uint4 v = *(const uint4*)((const u16*)content + gbase + (size_t)c * HW + w0);
        lds[c * 65 + w0 + 0] = b2f((u16)(v.x & 0xffffu));
        lds[c * 65 + w0 + 1] = b2f((u16)(v.x >> 16));
        lds[c * 65 + w0 + 2] = b2f((u16)(v.y & 0xffffu));
        lds[c * 65 + w0 + 3] = b2f((u16)(v.y >> 16));
        lds[c * 65 + w0 + 4] = b2f((u16)(v.z & 0xffffu));
        lds[c * 65 + w0 + 5] = b2f((u16)(v.z >> 16));
        lds[c * 65 + w0 + 6] = b2f((u16)(v.w & 0xffffu));
        lds[c * 65 + w0 + 7] = b2f((u16)(v.w >> 16));
    }
    __syncthreads();
    u32* out = (u32*)(cT + ((size_t)(b4 * 16 + ci) * 4096 + h * 64) * 32);
#pragma unroll
    for (int k = 0; k < 4; k++) {
        int j = tid + k * 256;          // 0..1023 u32 slots
        int w = j >> 4, cpair = j & 15;
        int key = (w + 1) & 3;
        int p0 = cpair << 1;            // physical u16 slot (even)
        int lc = (((p0 >> 3) ^ key) << 3) | (p0 & 7);
        u32 v = (u32)f2b(lds[lc * 65 + w]) | ((u32)f2b(lds[(lc + 1) * 65 + w]) << 16);
        out[j] = v;
    }
}

// ---------------------------------------------------------------------------
// Style stats: per (b,c) plane, 9 shifted window sums via inclusion-exclusion.
// ---------------------------------------------------------------------------
__global__ __launch_bounds__(256) void k_style_stats(const void* __restrict__ style,
        float* __restrict__ S, const int* __restrict__ flag) {
    int isf32 = *flag;
    int bc = blockIdx.x;                        // b*512 + c
    int base = bc * HW;
    int tid = threadIdx.x;
    float t = 0.f, top = 0.f, bot = 0.f, lft = 0.f, rgt = 0.f;
    for (int e = tid; e < HW; e += 256) {
        float v = ldin(style, base + e, isf32);
        int h = e >> 6, w = e & 63;
        t += v;
        top += (h == 0)  ? v : 0.f;
        bot += (h == 63) ? v : 0.f;
        lft += (w == 0)  ? v : 0.f;
        rgt += (w == 63) ? v : 0.f;
    }
#pragma unroll
    for (int off = 32; off > 0; off >>= 1) {
        t   += __shfl_down(t, off);
        top += __shfl_down(top, off);
        bot += __shfl_down(bot, off);
        lft += __shfl_down(lft, off);
        rgt += __shfl_down(rgt, off);
    }
    __shared__ float red[4][5];
    int wave = tid >> 6;
    if ((tid & 63) == 0) {
        red[wave][0] = t; red[wave][1] = top; red[wave][2] = bot;
        red[wave][3] = lft; red[wave][4] = rgt;
    }
    __syncthreads();
    if (tid == 0) {
        t   = red[0][0] + red[1][0] + red[2][0] + red[3][0];
        top = red[0][1] + red[1][1] + red[2][1] + red[3][1];
        bot = red[0][2] + red[1][2] + red[2][2] + red[3][2];
        lft = red[0][3] + red[1][3] + red[2][3] + red[3][3];
        rgt = red[0][4] + red[1][4] + red[2][4] + red[3][4];
        float c00 = ldin(style, base + 0,    isf32);
        float c0W = ldin(style, base + 63,   isf32);
        float cH0 = ldin(style, base + 4032, isf32);
        float cHW = ldin(style, base + 4095, isf32);
        float* o = S + bc * 9;
        o[0] = t - bot - rgt + cHW;
        o[1] = t - bot;
        o[2] = t - bot - lft + cH0;
        o[3] = t - rgt;
        o[4] = t;
        o[5] = t - lft;
        o[6] = t - top - rgt + c0W;
        o[7] = t - top;
        o[8] = t - top - lft + c00;
    }
}

// ---------------------------------------------------------------------------
// pooled[set,b,o] = (1/4096)*sum_{c,k} cw[o,c,k]*S[b,c,k] + cb[o]
// ---------------------------------------------------------------------------
__global__ __launch_bounds__(64) void k_pooled(const float* __restrict__ S,
        const void* __restrict__ cw1, const void* __restrict__ cb1,
        const void* __restrict__ cw2, const void* __restrict__ cb2,
        float* __restrict__ pooled, const int* __restrict__ flag) {
    int isf32 = *flag;
    int set = blockIdx.y;
    int b = blockIdx.x >> 5;
    int o = blockIdx.x & 31;
    const void* cw = set ? cw2 : cw1;
    const void* cb = set ? cb2 : cb1;
    int lane = threadIdx.x;
    float acc = 0.f;
    const float* Sb = S + b * NC * 9;
    int wbase = o * NC * 9;
    for (int c = lane; c < NC; c += 64) {
#pragma unroll
        for (int k = 0; k < 9; k++)
            acc += Sb[c * 9 + k] * ldin(cw, wbase + c * 9 + k, isf32);
    }
#pragma unroll
    for (int off = 32; off > 0; off >>= 1) acc += __shfl_down(acc, off);
    if (lane == 0)
        pooled[(set * NB + b) * INNER + o] = acc * (1.0f / 4096.0f) + ldin(cb, o, isf32);
}

// ---------------------------------------------------------------------------
// FC: f[b,row] = pooled[b,:]·fw[row,:] + fb[row]; written as bf16 MFMA
// B-fragments: fpack[(((bb*9 + t)*2 + nf)*64 + l)*8 + e], bb = set*8+b,
//   oc = nf*16+(l&15), ic = (l>>4)*8+e,  row = oc*288 + ic*9 + t.
// ---------------------------------------------------------------------------
__global__ __launch_bounds__(256) void k_fc(const float* __restrict__ pooled,
        const void* __restrict__ fw1, const void* __restrict__ fb1,
        const void* __restrict__ fw2, const void* __restrict__ fb2,
        u16* __restrict__ fpack, const int* __restrict__ flag) {
    int isf32 = *flag;
    int set = blockIdx.y;
    int b = blockIdx.x / 36;
    int chunk = blockIdx.x - b * 36;
    int row = chunk * 256 + threadIdx.x;       // 0..9215
    const void* fw = set ? fw2 : fw1;
    const void* fb = set ? fb2 : fb1;
    __shared__ float p[32];
    if (threadIdx.x < 32) p[threadIdx.x] = pooled[(set * NB + b) * 32 + threadIdx.x];
    __syncthreads();
    float acc = ldin(fb, row, isf32);
    if (isf32) {
        const float* fwf = (const float*)fw + row * 32;
#pragma unroll
        for (int j = 0; j < 32; j++) acc += fwf[j] * p[j];
    } else {
        const u32* w32 = (const u32*)((const u16*)fw + row * 32);
#pragma unroll
        for (int j = 0; j < 16; j++) {
            u32 u = w32[j];
            acc += b2f((u16)(u & 0xffffu)) * p[2 * j];
            acc += b2f((u16)(u >> 16)) * p[2 * j + 1];
        }
    }
    int oc = row / 288;
    int rem = row - oc * 288;
    int ic = rem / 9;
    int t9 = rem - ic * 9;
    int l = (oc & 15) | ((ic >> 3) << 4);
    int e = ic & 7;
    int nf = oc >> 4;
    fpack[((((set * NB + b) * 9 + t9) * 2 + nf) * 64 + l) * 8 + e] = f2b(acc);
}

// ---------------------------------------------------------------------------
// Conv 512->32 (MFMA implicit GEMM) reading pre-transposed+swizzled cT.
// One block per (b4,row); 4 waves, each a 16-pixel M-tile x 32 oc.
// 16 chunks of 32 channels, staged via global_load_lds (coalesced, linear).
// A-read XORs c-group by (wi&3) to undo the baked swizzle (bank-spread).
// Output: c0T[b][h][w][32] bf16 (+bias), swizzled with key ((w+1)&3).
// ---------------------------------------------------------------------------
__global__ __launch_bounds__(256) void k_conv_down(const u16* __restrict__ cT,
        const u16* __restrict__ Bp, const void* __restrict__ dsb,
        u16* __restrict__ c0T, int bstart, const int* __restrict__ flag) {
    int isf32 = *flag;
    int b4 = blockIdx.x >> 6, row = blockIdx.x & 63;
    int b = bstart + b4;
    int tid = threadIdx.x, lane = tid & 63;
    int wid = __builtin_amdgcn_readfirstlane(tid >> 6);
    __shared__ u16 lds[3 * 66 * 32];
    u32* lds32 = (u32*)lds;
    // zero everything once: halo cols + out-of-range rows stay zero forever
    for (int i = tid; i < 3 * 66 * 16; i += 256) lds32[i] = 0u;
    __syncthreads();

    int m = lane & 15, g = lane >> 4;
    int wbase = wid * 16;
    int j = wid * 64 + lane;            // 0..255 staging slot
    f32x4 acc0 = {0.f, 0.f, 0.f, 0.f}, acc1 = {0.f, 0.f, 0.f, 0.f};

    for (int ci = 0; ci < 16; ci++) {
        if (ci) __syncthreads();
        const u16* sp = cT + ((size_t)(b4 * 16 + ci) * 4096) * 32;
#pragma unroll
        for (int r = 0; r < 3; r++) {
            int gh = row + r - 1;
            if (gh >= 0 && gh < 64)
                gld_lds16(sp + (size_t)gh * 2048 + j * 8,
                          (char*)lds + (r * 66 + 1) * 64 + wid * 1024);
        }
        __syncthreads();
#pragma unroll
        for (int t9 = 0; t9 < 9; t9++) {
            int dh = t9 / 3, dw = t9 - dh * 3;
            int wi = wbase + m + dw;
            bf16x8 a = *(const bf16x8*)(lds + ((dh * 66 + wi) * 32 + (g ^ (wi & 3)) * 8));
            bf16x8 b0 = ((const bf16x8*)Bp)[((t9 * 16 + ci) * 2 + 0) * 64 + lane];
            bf16x8 b1 = ((const bf16x8*)Bp)[((t9 * 16 + ci) * 2 + 1) * 64 + lane];
            acc0 = __builtin_amdgcn_mfma_f32_16x16x32_bf16(a, b0, acc0, 0, 0, 0);
            acc1 = __builtin_amdgcn_mfma_f32_16x16x32_bf16(a, b1, acc1, 0, 0, 0);
        }
    }
    // epilogue: D col=lane&15 -> oc, row=(lane>>4)*4+r -> pixel; swizzled store
    float bia0 = ldin(dsb, m, isf32);
    float bia1 = ldin(dsb, 16 + m, isf32);
    size_t obase = ((size_t)b * 4096 + row * 64) * 32;
    int pix0 = wbase + g * 4;
#pragma unroll
    for (int r = 0; r < 4; r++) {
        int w = pix0 + r;
        int key = (w + 1) & 3;
        int p0 = (((m >> 3) ^ key) << 3) | (m & 7);
        int p1 = ((((16 + m) >> 3) ^ key) << 3) | (m & 7);
        c0T[obase + (size_t)w * 32 + p0] = f2b(acc0[r] + bia0);
        c0T[obase + (size_t)w * 32 + p1] = f2b(acc1[r] + bia1);
    }
}

// ---------------------------------------------------------------------------
// Per-sample dynamic 32->32 conv (MFMA) + optional LeakyReLU.
// srcT/dstT: [b][h][w][32] bf16, swizzled (key (w+1)&3). Staged linear.
// ---------------------------------------------------------------------------
__global__ __launch_bounds__(256) void k_apply(const u16* __restrict__ srcT,
        const u16* __restrict__ fpack, u16* __restrict__ dstT, int lrelu) {
    int b = blockIdx.x >> 6, row = blockIdx.x & 63;
    int tid = threadIdx.x, lane = tid & 63;
    int wid = __builtin_amdgcn_readfirstlane(tid >> 6);
    __shared__ u16 lds[3 * 66 * 32];
    u32* lds32 = (u32*)lds;
    for (int i = tid; i < 96; i += 256) {
        int r = i >> 5, side = (i >> 4) & 1, cpr = i & 15;
        lds32[(r * 66 + side * 65) * 16 + cpr] = 0u;
    }
    const u16* sp = srcT + (size_t)b * 64 * 64 * 32;
    for (int r = 0; r < 3; r++) {
        int gh = row + r - 1;
        u32 ldsoff = (u32)(r * 66 + 1) * 64 + (u32)wid * 1024;  // bytes
        if (gh >= 0 && gh < 64) {
            int j = wid * 64 + lane;
            gld_lds16(sp + (size_t)gh * 2048 + j * 8, (char*)lds + ldsoff);
        } else {
            int4 z = make_int4(0, 0, 0, 0);
            *(int4*)((char*)lds + ldsoff + (u32)lane * 16) = z;
        }
    }
    __syncthreads();

    int m = lane & 15, g = lane >> 4, wbase = wid * 16;
    f32x4 acc0 = {0.f, 0.f, 0.f, 0.f}, acc1 = {0.f, 0.f, 0.f, 0.f};
    const bf16x8* FB = (const bf16x8*)fpack + (size_t)b * 1152;
#pragma unroll
    for (int t9 = 0; t9 < 9; t9++) {
        int dh = t9 / 3, dw = t9 - dh * 3;
        int wi = wbase + m + dw;
        bf16x8 a = *(const bf16x8*)(lds + ((dh * 66 + wi) * 32 + (g ^ (wi & 3)) * 8));
        bf16x8 b0 = FB[(t9 * 2 + 0) * 64 + lane];
        bf16x8 b1 = FB[(t9 * 2 + 1) * 64 + lane];
        acc0 = __builtin_amdgcn_mfma_f32_16x16x32_bf16(a, b0, acc0, 0, 0, 0);
        acc1 = __builtin_amdgcn_mfma_f32_16x16x32_bf16(a, b1, acc1, 0, 0, 0);
    }
    size_t obase = ((size_t)(b * 64 + row) * 64) * 32;
    int pix0 = wbase + g * 4;
#pragma unroll
    for (int r = 0; r < 4; r++) {
        float v0 = acc0[r], v1 = acc1[r];
        if (lrelu) {
            v0 = (v0 >= 0.f) ? v0 : 0.2f * v0;
            v1 = (v1 >= 0.f) ? v1 : 0.2f * v1;
        }
        int w = pix0 + r;
        int key = (w + 1) & 3;
        int p0 = (((m >> 3) ^ key) << 3) | (m & 7);
        int p1 = ((((16 + m) >> 3) ^ key) << 3) | (m & 7);
        dstT[obase + (size_t)w * 32 + p0] = f2b(v0);
        dstT[obase + (size_t)w * 32 + p1] = f2b(v1);
    }
}

// ---------------------------------------------------------------------------
// Conv 32->512 (MFMA) + bias + residual content -> out (dtype per flag).
// blockIdx.y = quarter of output channels (128 oc = 8 N-frags).
// ---------------------------------------------------------------------------
__global__ __launch_bounds__(256) void k_conv_up(const u16* __restrict__ c2T,
        const u16* __restrict__ B2p, const void* __restrict__ upb,
        const void* __restrict__ content, void* __restrict__ outv,
        const int* __restrict__ flag) {
    int isf32 = *flag;
    int b = blockIdx.x >> 6, row = blockIdx.x & 63;
    int nq = blockIdx.y;                           // 0..3
    int tid = threadIdx.x, lane = tid & 63;
    int wid = __builtin_amdgcn_readfirstlane(tid >> 6);
    __shared__ u16 lds[3 * 66 * 32];
    u32* lds32 = (u32*)lds;
    for (int i = tid; i < 96; i += 256) {
        int r = i >> 5, side = (i >> 4) & 1, cpr = i & 15;
        lds32[(r * 66 + side * 65) * 16 + cpr] = 0u;
    }
    const u16* sp = c2T + (size_t)b * 64 * 64 * 32;
    for (int r = 0; r < 3; r++) {
        int gh = row + r - 1;
        u32 ldsoff = (u32)(r * 66 + 1) * 64 + (u32)wid * 1024;
        if (gh >= 0 && gh < 64) {
            int j = wid * 64 + lane;
            gld_lds16(sp + (size_t)gh * 2048 + j * 8, (char*)lds + ldsoff);
        } else {
            int4 z = make_int4(0, 0, 0, 0);
            *(int4*)((char*)lds + ldsoff + (u32)lane * 16) = z;
        }
    }
    __syncthreads();

    int m = lane & 15, g = lane >> 4, wbase = wid * 16;
    f32x4 acc[8];
#pragma unroll
    for (int i = 0; i < 8; i++) acc[i] = (f32x4){0.f, 0.f, 0.f, 0.f};
#pragma unroll
    for (int t9 = 0; t9 < 9; t9++) {
        int dh = t9 / 3, dw = t9 - dh * 3;
        int wi = wbase + m + dw;
        bf16x8 a = *(const bf16x8*)(lds + ((dh * 66 + wi) * 32 + (g ^ (wi & 3)) * 8));
#pragma unroll
        for (int nfl = 0; nfl < 8; nfl++) {
            bf16x8 bw = ((const bf16x8*)B2p)[(t9 * 32 + nq * 8 + nfl) * 64 + lane];
            acc[nfl] = __builtin_amdgcn_mfma_f32_16x16x32_bf16(a, bw, acc[nfl], 0, 0, 0);
        }
    }
    int pix0 = wbase + g * 4;
#pragma unroll
    for (int nfl = 0; nfl < 8; nfl++) {
        int oc = nq * 128 + nfl * 16 + m;
        size_t idx = ((size_t)b * NC + oc) * HW + (size_t)row * 64 + pix0;
        float bias = ldin(upb, oc, isf32);
        if (isf32) {
            f32x4 rsd = *(const f32x4*)((const float*)content + idx);
            f32x4 v;
#pragma unroll
            for (int r = 0; r < 4; r++) v[r] = acc[nfl][r] + bias + rsd[r];
            *(f32x4*)((float*)outv + idx) = v;
        } else {
#pragma unroll
            for (int r = 0; r < 4; r++) {
                float rv = b2f(((const u16*)content)[idx + r]);
                ((u16*)outv)[idx + r] = f2b(acc[nfl][r] + bias + rv);
            }
        }
    }
}

// ---------------------------------------------------------------------------
extern "C" void kernel_launch(void* const* d_in, const int* in_sizes, int n_in,
                              void* d_out, int out_size, void* d_ws, size_t ws_size,
                              hipStream_t stream) {
    const void* content = d_in[0];
    const void* style   = d_in[1];
    const void* ds_w    = d_in[2];
    const void* ds_b    = d_in[3];
    const void* up_w    = d_in[4];
    const void* up_b    = d_in[5];
    const void* f1_cw   = d_in[6];
    const void* f1_cb   = d_in[7];
    const void* f1_fw   = d_in[8];
    const void* f1_fb   = d_in[9];
    const void* f2_cw   = d_in[10];
    const void* f2_cb   = d_in[11];
    const void* f2_fw   = d_in[12];
    const void* f2_fb   = d_in[13];

    // d_out doubles as scratch for everything DEAD before the final kernel.
    // Worst-case capacity (bf16 out): 8,388,608 f32. Used: ~5.43M f32.
    // The final kernel (k_conv_up) reads NOTHING from d_out.
    float* S      = (float*)d_out;               //    36,864 f32
    float* pooled = S + 36864;                   //       512 f32
    u16*   fpack  = (u16*)(pooled + 512);        //   147,456 u16 (both sets)
    u16*   Bpack  = fpack + 147456;              //   147,456 u16
    u16*   c0T    = Bpack + 147456;              // 1,048,576 u16
    u16*   c1T    = c0T + 1048576;               // 1,048,576 u16
    u16*   cTh    = c1T + 1048576;               // 8,388,608 u16 (half-batch cT)

    // d_ws holds ONLY what the final kernel reads: 2,392,080 bytes.
    int*   flag   = (int*)d_ws;
    u16*   B2pack = (u16*)((char*)d_ws + 16);    //   147,456 u16
    u16*   c2T    = B2pack + 147456;             // 1,048,576 u16

    k_detect<<<1, 256, 0, stream>>>((const u16*)content, flag);
    k_prep_wdown<<<576, 256, 0, stream>>>(ds_w, Bpack, flag);
    k_prep_wup<<<576, 256, 0, stream>>>(up_w, B2pack, flag);
    k_style_stats<<<NB * NC, 256, 0, stream>>>(style, S, flag);
    k_pooled<<<dim3(NB * 32, 2), 64, 0, stream>>>(S, f1_cw, f1_cb, f2_cw, f2_cb, pooled, flag);
    k_fc<<<dim3(NB * 36, 2), 256, 0, stream>>>(pooled, f1_fw, f1_fb, f2_fw, f2_fb, fpack, flag);
    // content transpose + downsample conv, in two batch-halves (cT reused;
    // stream order serializes transform/conv pairs)
    for (int half = 0; half < 2; half++) {
        int bstart = half * 4;
        k_transform<<<4 * 16 * 64, 256, 0, stream>>>(content, cTh, bstart, flag);
        k_conv_down<<<4 * 64, 256, 0, stream>>>(cTh, Bpack, ds_b, c0T, bstart, flag);
    }
    k_apply<<<NB * 64, 256, 0, stream>>>(c0T, fpack, c1T, 1);
    k_apply<<<NB * 64, 256, 0, stream>>>(c1T, fpack + NB * 9216, c2T, 0);
    k_conv_up<<<dim3(NB * 64, 4), 256, 0, stream>>>(c2T, B2pack, up_b, content, d_out, flag);
}

// Round 4
// 283.582 us; speedup vs baseline: 3.3044x; 1.1668x over previous
//
#include <hip/hip_runtime.h>
#include <hip/hip_bf16.h>

// Problem constants
#define NB 8
#define NC 512
#define HW 4096
#define INNER 32

typedef unsigned short u16;
typedef unsigned int u32;
typedef __attribute__((ext_vector_type(8))) short bf16x8;   // 8 bf16 = 4 VGPRs
typedef __attribute__((ext_vector_type(4))) float f32x4;    // MFMA C/D

__device__ __forceinline__ float b2f(u16 u) {
    union { u32 a; float f; } z;
    z.a = ((u32)u) << 16;
    return z.f;
}

// fp32 -> bf16 with round-to-nearest-even
__device__ __forceinline__ u16 f2b(float v) {
    u32 x = __float_as_uint(v);
    return (u16)((x + 0x7fffu + ((x >> 16) & 1u)) >> 16);
}

// Dtype-flexible input load. isf32: 1 = fp32 tensors, 0 = bf16 tensors.
__device__ __forceinline__ float ldin(const void* p, int idx, int isf32) {
    if (isf32) return ((const float*)p)[idx];
    return b2f(((const u16*)p)[idx]);
}

// async global->LDS, 16 B per lane, dest = wave-uniform base + lane*16
__device__ __forceinline__ void gld_lds16(const void* g, void* l) {
    __builtin_amdgcn_global_load_lds(
        (const __attribute__((address_space(1))) unsigned int*)g,
        (__attribute__((address_space(3))) unsigned int*)l, 16, 0, 0);
}

// Resolve input dtype. hisf >= 0: trusted host answer (from exact in_sizes
// match). Otherwise: wave-level bit-pattern ballot on `content` (bf16 N(0,1)
// u16s have exponent in [100,150] w.p. ~1; fp32 low-words ~0.2).
__device__ __forceinline__ int resolve_isf32(int hisf, const void* content) {
    if (hisf >= 0) return hisf;
    int lane = threadIdx.x & 63;
    u16 u = ((const u16*)content)[lane * 2048];
    int e = (u >> 7) & 0xff;
    unsigned long long m = __ballot(e >= 100 && e <= 150);
    return (__popcll(m) < 32) ? 1 : 0;
}

// ===========================================================================
// Role bodies (merged-launch building blocks)
// ===========================================================================

// Style stats: per (b,c) plane, 9 shifted window sums via inclusion-exclusion.
__device__ __forceinline__ void role_style(int bc, const void* style, float* S,
                                           int isf32, float* smf) {
    int base = bc * HW;
    int tid = threadIdx.x;
    float t = 0.f, top = 0.f, bot = 0.f, lft = 0.f, rgt = 0.f;
    for (int e = tid; e < HW; e += 256) {
        float v = ldin(style, base + e, isf32);
        int h = e >> 6, w = e & 63;
        t += v;
        top += (h == 0)  ? v : 0.f;
        bot += (h == 63) ? v : 0.f;
        lft += (w == 0)  ? v : 0.f;
        rgt += (w == 63) ? v : 0.f;
    }
#pragma unroll
    for (int off = 32; off > 0; off >>= 1) {
        t   += __shfl_down(t, off);
        top += __shfl_down(top, off);
        bot += __shfl_down(bot, off);
        lft += __shfl_down(lft, off);
        rgt += __shfl_down(rgt, off);
    }
    int wave = tid >> 6;
    if ((tid & 63) == 0) {
        smf[wave * 5 + 0] = t; smf[wave * 5 + 1] = top; smf[wave * 5 + 2] = bot;
        smf[wave * 5 + 3] = lft; smf[wave * 5 + 4] = rgt;
    }
    __syncthreads();
    if (tid == 0) {
        t   = smf[0] + smf[5] + smf[10] + smf[15];
        top = smf[1] + smf[6] + smf[11] + smf[16];
        bot = smf[2] + smf[7] + smf[12] + smf[17];
        lft = smf[3] + smf[8] + smf[13] + smf[18];
        rgt = smf[4] + smf[9] + smf[14] + smf[19];
        float c00 = ldin(style, base + 0,    isf32);
        float c0W = ldin(style, base + 63,   isf32);
        float cH0 = ldin(style, base + 4032, isf32);
        float cHW = ldin(style, base + 4095, isf32);
        float* o = S + bc * 9;
        o[0] = t - bot - rgt + cHW;
        o[1] = t - bot;
        o[2] = t - bot - lft + cH0;
        o[3] = t - rgt;
        o[4] = t;
        o[5] = t - lft;
        o[6] = t - top - rgt + c0W;
        o[7] = t - top;
        o[8] = t - top - lft + c00;
    }
}

// Transpose content [b][c][h][w] -> cT [(b4*16+ci)][h][w][32] bf16 with the
// c-group XOR swizzle baked in (key (w+1)&3).
__device__ __forceinline__ void role_transform(int ridx, const void* content,
        u16* cT, int bstart, int isf32, float* lds) {
    int h  = ridx & 63;
    int ci = (ridx >> 6) & 15;
    int b4 = ridx >> 10;
    int tid = threadIdx.x;
    size_t gbase = ((size_t)(bstart + b4) * NC + ci * 32) * HW + (size_t)h * 64;
    if (isf32) {
#pragma unroll
        for (int k = 0; k < 2; k++) {
            int q = tid + k * 256;                  // 0..511 float4s
            int c = q >> 4, w0 = (q & 15) * 4;
            float4 v = *(const float4*)((const float*)content + gbase + (size_t)c * HW + w0);
            lds[c * 65 + w0 + 0] = v.x;
            lds[c * 65 + w0 + 1] = v.y;
            lds[c * 65 + w0 + 2] = v.z;
            lds[c * 65 + w0 + 3] = v.w;
        }
    } else {
        int c = tid >> 3, w0 = (tid & 7) * 8;
        uint4 v = *(const uint4*)((const u16*)content + gbase + (size_t)c * HW + w0);
        lds[c * 65 + w0 + 0] = b2f((u16)(v.x & 0xffffu));
        lds[c * 65 + w0 + 1] = b2f((u16)(v.x >> 16));
        lds[c * 65 + w0 + 2] = b2f((u16)(v.y & 0xffffu));
        lds[c * 65 + w0 + 3] = b2f((u16)(v.y >> 16));
        lds[c * 65 + w0 + 4] = b2f((u16)(v.z & 0xffffu));
        lds[c * 65 + w0 + 5] = b2f((u16)(v.z >> 16));
        lds[c * 65 + w0 + 6] = b2f((u16)(v.w & 0xffffu));
        lds[c * 65 + w0 + 7] = b2f((u16)(v.w >> 16));
    }
    __syncthreads();
    u32* out = (u32*)(cT + ((size_t)(b4 * 16 + ci) * 4096 + h * 64) * 32);
#pragma unroll
    for (int k = 0; k < 4; k++) {
        int j = tid + k * 256;          // 0..1023 u32 slots
        int w = j >> 4, cpair = j & 15;
        int key = (w + 1) & 3;
        int p0 = cpair << 1;
        int lc = (((p0 >> 3) ^ key) << 3) | (p0 & 7);
        u32 v = (u32)f2b(lds[lc * 65 + w]) | ((u32)f2b(lds[(lc + 1) * 65 + w]) << 16);
        out[j] = v;
    }
}

// Pack ds_w [32][512][3][3] -> MFMA B-fragments (bf16).
__device__ __forceinline__ void role_prep_wdown(int ridx, const void* dsw,
        u16* Bp, int isf32) {
    int idx = ridx * 256 + threadIdx.x;             // < 147456
    int e = idx & 7, l = (idx >> 3) & 63, nf = (idx >> 9) & 1;
    int cb = (idx >> 10) & 15, t9 = idx >> 14;
    int oc = nf * 16 + (l & 15);
    int c = cb * 32 + (l >> 4) * 8 + e;
    Bp[idx] = f2b(ldin(dsw, (oc * NC + c) * 9 + t9, isf32));
}

// Pack up_w [512][32][3][3] -> B2_pack.
__device__ __forceinline__ void role_prep_wup(int ridx, const void* upw,
        u16* B2p, int isf32) {
    int idx = ridx * 256 + threadIdx.x;             // < 147456
    int e = idx & 7, l = (idx >> 3) & 63, nfo = (idx >> 9) & 31, t9 = idx >> 14;
    int oc = nfo * 16 + (l & 15);
    int ic = (l >> 4) * 8 + e;
    B2p[idx] = f2b(ldin(upw, (oc * INNER + ic) * 9 + t9, isf32));
}

// FC: f[b,row] = pooled[b,:]·fw[row,:] + fb[row]; written as MFMA B-frags.
__device__ __forceinline__ void role_fc(int ridx, const float* pooled,
        const void* fw1, const void* fb1, const void* fw2, const void* fb2,
        u16* fpack, int isf32, float* p) {
    int set = ridx / 288;
    int rr = ridx - set * 288;
    int b = rr / 36;
    int chunk = rr - b * 36;
    int row = chunk * 256 + threadIdx.x;       // 0..9215
    const void* fw = set ? fw2 : fw1;
    const void* fb = set ? fb2 : fb1;
    if (threadIdx.x < 32) p[threadIdx.x] = pooled[(set * NB + b) * 32 + threadIdx.x];
    __syncthreads();
    float acc = ldin(fb, row, isf32);
    if (isf32) {
        const float* fwf = (const float*)fw + row * 32;
#pragma unroll
        for (int j = 0; j < 32; j++) acc += fwf[j] * p[j];
    } else {
        const u32* w32 = (const u32*)((const u16*)fw + row * 32);
#pragma unroll
        for (int j = 0; j < 16; j++) {
            u32 u = w32[j];
            acc += b2f((u16)(u & 0xffffu)) * p[2 * j];
            acc += b2f((u16)(u >> 16)) * p[2 * j + 1];
        }
    }
    int oc = row / 288;
    int rem = row - oc * 288;
    int ic = rem / 9;
    int t9 = rem - ic * 9;
    int l = (oc & 15) | ((ic >> 3) << 4);
    int e = ic & 7;
    int nf = oc >> 4;
    fpack[((((set * NB + b) * 9 + t9) * 2 + nf) * 64 + l) * 8 + e] = f2b(acc);
}

// Conv 512->32 MFMA implicit GEMM, reading pre-transposed+swizzled cT.
__device__ __forceinline__ void role_conv_down(int x, const u16* cT,
        const u16* Bp, const void* dsb, u16* c0T, int bstart, int isf32,
        u16* lds) {
    u32* lds32 = (u32*)lds;
    int b4 = x >> 6, row = x & 63;
    int b = bstart + b4;
    int tid = threadIdx.x, lane = tid & 63;
    int wid = __builtin_amdgcn_readfirstlane(tid >> 6);
    // zero everything once: halo cols + out-of-range rows stay zero forever
    for (int i = tid; i < 3 * 66 * 16; i += 256) lds32[i] = 0u;
    __syncthreads();

    int m = lane & 15, g = lane >> 4;
    int wbase = wid * 16;
    f32x4 acc0 = {0.f, 0.f, 0.f, 0.f}, acc1 = {0.f, 0.f, 0.f, 0.f};

    for (int ci = 0; ci < 16; ci++) {
        if (ci) __syncthreads();
        const u16* sp = cT + ((size_t)(b4 * 16 + ci) * 4096) * 32;
#pragma unroll
        for (int r = 0; r < 3; r++) {
            int gh = row + r - 1;
            if (gh >= 0 && gh < 64)
                gld_lds16(sp + (size_t)gh * 2048 + tid * 8,
                          (char*)lds + (r * 66 + 1) * 64 + wid * 1024);
        }
        __syncthreads();
#pragma unroll
        for (int t9 = 0; t9 < 9; t9++) {
            int dh = t9 / 3, dw = t9 - dh * 3;
            int wi = wbase + m + dw;
            bf16x8 a = *(const bf16x8*)(lds + ((dh * 66 + wi) * 32 + ((g ^ (wi & 3)) * 8)));
            bf16x8 b0 = ((const bf16x8*)Bp)[((t9 * 16 + ci) * 2 + 0) * 64 + lane];
            bf16x8 b1 = ((const bf16x8*)Bp)[((t9 * 16 + ci) * 2 + 1) * 64 + lane];
            acc0 = __builtin_amdgcn_mfma_f32_16x16x32_bf16(a, b0, acc0, 0, 0, 0);
            acc1 = __builtin_amdgcn_mfma_f32_16x16x32_bf16(a, b1, acc1, 0, 0, 0);
        }
    }
    float bia0 = ldin(dsb, m, isf32);
    float bia1 = ldin(dsb, 16 + m, isf32);
    size_t obase = ((size_t)b * 4096 + row * 64) * 32;
    int pix0 = wbase + g * 4;
#pragma unroll
    for (int r = 0; r < 4; r++) {
        int w = pix0 + r;
        int key = (w + 1) & 3;
        int p0 = (((m >> 3) ^ key) << 3) | (m & 7);
        int p1 = ((((16 + m) >> 3) ^ key) << 3) | (m & 7);
        c0T[obase + (size_t)w * 32 + p0] = f2b(acc0[r] + bia0);
        c0T[obase + (size_t)w * 32 + p1] = f2b(acc1[r] + bia1);
    }
}

// pooled[set,b,o]: one wave per (set,b,o).
__device__ __forceinline__ void role_pooled(int p, const float* S,
        const void* cw1, const void* cb1, const void* cw2, const void* cb2,
        float* pooled, int isf32) {
    int tid = threadIdx.x;
    int pair = p * 4 + (tid >> 6);               // 0..511
    int set = pair >> 8;
    int rem = pair & 255;
    int b = rem >> 5;
    int o = rem & 31;
    const void* cw = set ? cw2 : cw1;
    const void* cb = set ? cb2 : cb1;
    int lane = tid & 63;
    float acc = 0.f;
    const float* Sb = S + b * NC * 9;
    int wbase = o * NC * 9;
    for (int c = lane; c < NC; c += 64) {
#pragma unroll
        for (int k = 0; k < 9; k++)
            acc += Sb[c * 9 + k] * ldin(cw, wbase + c * 9 + k, isf32);
    }
#pragma unroll
    for (int off = 32; off > 0; off >>= 1) acc += __shfl_down(acc, off);
    if (lane == 0)
        pooled[(set * NB + b) * INNER + o] = acc * (1.0f / 4096.0f) + ldin(cb, o, isf32);
}

// ===========================================================================
// Merged launches
// ===========================================================================

// Front: style_stats | transform | prep_wdown | prep_wup | fc
__global__ __launch_bounds__(256) void k_front(
        const void* __restrict__ style, float* __restrict__ S, int nStyle,
        const void* __restrict__ content, u16* __restrict__ cT, int bstart, int nT,
        const void* __restrict__ dsw, u16* __restrict__ Bp,
        const void* __restrict__ upw, u16* __restrict__ B2p, int nPrep,
        const float* __restrict__ pooled,
        const void* __restrict__ fw1, const void* __restrict__ fb1,
        const void* __restrict__ fw2, const void* __restrict__ fb2,
        u16* __restrict__ fpack, int hisf) {
    __shared__ float smf[32 * 65];
    int isf32 = resolve_isf32(hisf, content);
    int x = blockIdx.x;
    if (x < nStyle) { role_style(x, style, S, isf32, smf); return; }
    x -= nStyle;
    if (x < nT) { role_transform(x, content, cT, bstart, isf32, smf); return; }
    x -= nT;
    if (x < nPrep) { role_prep_wdown(x, dsw, Bp, isf32); return; }
    x -= nPrep;
    if (x < nPrep) { role_prep_wup(x, upw, B2p, isf32); return; }
    x -= nPrep;
    role_fc(x, pooled, fw1, fb1, fw2, fb2, fpack, isf32, smf);
}

// Mid: conv_down | pooled
__global__ __launch_bounds__(256) void k_mid(
        const u16* __restrict__ cT, const u16* __restrict__ Bp,
        const void* __restrict__ dsb, u16* __restrict__ c0T, int bstart, int nCD,
        const float* __restrict__ S,
        const void* __restrict__ cw1, const void* __restrict__ cb1,
        const void* __restrict__ cw2, const void* __restrict__ cb2,
        float* __restrict__ pooled, const void* __restrict__ content, int hisf) {
    __shared__ u16 lds[3 * 66 * 32];
    int isf32 = resolve_isf32(hisf, content);
    int x = blockIdx.x;
    if (x < nCD) { role_conv_down(x, cT, Bp, dsb, c0T, bstart, isf32, lds); return; }
    role_pooled(x - nCD, S, cw1, cb1, cw2, cb2, pooled, isf32);
}

// ---------------------------------------------------------------------------
// Per-sample dynamic 32->32 conv (MFMA) + optional LeakyReLU.
// srcT/dstT: [b][h][w][32] bf16, swizzled (key (w+1)&3). Staged linear.
// ---------------------------------------------------------------------------
__global__ __launch_bounds__(256) void k_apply(const u16* __restrict__ srcT,
        const u16* __restrict__ fpack, u16* __restrict__ dstT, int lrelu) {
    int b = blockIdx.x >> 6, row = blockIdx.x & 63;
    int tid = threadIdx.x, lane = tid & 63;
    int wid = __builtin_amdgcn_readfirstlane(tid >> 6);
    __shared__ u16 lds[3 * 66 * 32];
    u32* lds32 = (u32*)lds;
    for (int i = tid; i < 96; i += 256) {
        int r = i >> 5, side = (i >> 4) & 1, cpr = i & 15;
        lds32[(r * 66 + side * 65) * 16 + cpr] = 0u;
    }
    const u16* sp = srcT + (size_t)b * 64 * 64 * 32;
    for (int r = 0; r < 3; r++) {
        int gh = row + r - 1;
        u32 ldsoff = (u32)(r * 66 + 1) * 64 + (u32)wid * 1024;  // bytes
        if (gh >= 0 && gh < 64) {
            gld_lds16(sp + (size_t)gh * 2048 + tid * 8, (char*)lds + ldsoff);
        } else {
            int4 z = make_int4(0, 0, 0, 0);
            *(int4*)((char*)lds + ldsoff + (u32)lane * 16) = z;
        }
    }
    __syncthreads();

    int m = lane & 15, g = lane >> 4, wbase = wid * 16;
    f32x4 acc0 = {0.f, 0.f, 0.f, 0.f}, acc1 = {0.f, 0.f, 0.f, 0.f};
    const bf16x8* FB = (const bf16x8*)fpack + (size_t)b * 1152;
#pragma unroll
    for (int t9 = 0; t9 < 9; t9++) {
        int dh = t9 / 3, dw = t9 - dh * 3;
        int wi = wbase + m + dw;
        bf16x8 a = *(const bf16x8*)(lds + ((dh * 66 + wi) * 32 + ((g ^ (wi & 3)) * 8)));
        bf16x8 b0 = FB[(t9 * 2 + 0) * 64 + lane];
        bf16x8 b1 = FB[(t9 * 2 + 1) * 64 + lane];
        acc0 = __builtin_amdgcn_mfma_f32_16x16x32_bf16(a, b0, acc0, 0, 0, 0);
        acc1 = __builtin_amdgcn_mfma_f32_16x16x32_bf16(a, b1, acc1, 0, 0, 0);
    }
    size_t obase = ((size_t)(b * 64 + row) * 64) * 32;
    int pix0 = wbase + g * 4;
#pragma unroll
    for (int r = 0; r < 4; r++) {
        float v0 = acc0[r], v1 = acc1[r];
        if (lrelu) {
            v0 = (v0 >= 0.f) ? v0 : 0.2f * v0;
            v1 = (v1 >= 0.f) ? v1 : 0.2f * v1;
        }
        int w = pix0 + r;
        int key = (w + 1) & 3;
        int p0 = (((m >> 3) ^ key) << 3) | (m & 7);
        int p1 = ((((16 + m) >> 3) ^ key) << 3) | (m & 7);
        dstT[obase + (size_t)w * 32 + p0] = f2b(v0);
        dstT[obase + (size_t)w * 32 + p1] = f2b(v1);
    }
}

// ---------------------------------------------------------------------------
// Conv 32->512 (MFMA) + bias + residual -> out. blockIdx.y = oc quarter.
// Epilogue bounced through LDS [oc][px] (stride 68, 2 halves of 64 oc) so
// the residual loads and output stores are 16-lane-contiguous (256 B).
// ---------------------------------------------------------------------------
__global__ __launch_bounds__(256) void k_conv_up(const u16* __restrict__ c2T,
        const u16* __restrict__ B2p, const void* __restrict__ upb,
        const void* __restrict__ content, void* __restrict__ outv, int hisf) {
    int isf32 = resolve_isf32(hisf, content);
    int b = blockIdx.x >> 6, row = blockIdx.x & 63;
    int nq = blockIdx.y;                           // 0..3
    int tid = threadIdx.x, lane = tid & 63;
    int wid = __builtin_amdgcn_readfirstlane(tid >> 6);
    __shared__ char smem[64 * 68 * 4] __attribute__((aligned(16)));  // 17408 B
    u16* lds = (u16*)smem;
    u32* lds32 = (u32*)smem;
    for (int i = tid; i < 96; i += 256) {
        int r = i >> 5, side = (i >> 4) & 1, cpr = i & 15;
        lds32[(r * 66 + side * 65) * 16 + cpr] = 0u;
    }
    const u16* sp = c2T + (size_t)b * 64 * 64 * 32;
    for (int r = 0; r < 3; r++) {
        int gh = row + r - 1;
        u32 ldsoff = (u32)(r * 66 + 1) * 64 + (u32)wid * 1024;
        if (gh >= 0 && gh < 64) {
            gld_lds16(sp + (size_t)gh * 2048 + tid * 8, (char*)lds + ldsoff);
        } else {
            int4 z = make_int4(0, 0, 0, 0);
            *(int4*)((char*)lds + ldsoff + (u32)lane * 16) = z;
        }
    }
    __syncthreads();

    int m = lane & 15, g = lane >> 4, wbase = wid * 16;
    f32x4 acc[8];
#pragma unroll
    for (int i = 0; i < 8; i++) acc[i] = (f32x4){0.f, 0.f, 0.f, 0.f};
#pragma unroll
    for (int t9 = 0; t9 < 9; t9++) {
        int dh = t9 / 3, dw = t9 - dh * 3;
        int wi = wbase + m + dw;
        bf16x8 a = *(const bf16x8*)(lds + ((dh * 66 + wi) * 32 + ((g ^ (wi & 3)) * 8)));
#pragma unroll
        for (int nfl = 0; nfl < 8; nfl++) {
            bf16x8 bw = ((const bf16x8*)B2p)[(t9 * 32 + nq * 8 + nfl) * 64 + lane];
            acc[nfl] = __builtin_amdgcn_mfma_f32_16x16x32_bf16(a, bw, acc[nfl], 0, 0, 0);
        }
    }

    // Coalesced epilogue via LDS: two halves of 64 oc, [ocl][px] stride 68.
    int pix0 = wbase + g * 4;
    float* fl = (float*)smem;
    int ocl2 = tid >> 4;            // 0..15
    int px0 = (tid & 15) * 4;       // 0..60
    __syncthreads();                // input tile dead
#pragma unroll
    for (int hf = 0; hf < 2; hf++) {
        if (hf) __syncthreads();
#pragma unroll
        for (int nf = 0; nf < 4; nf++) {
            int ocl = nf * 16 + m;
            *(f32x4*)(fl + ocl * 68 + pix0) = acc[hf * 4 + nf];
        }
        __syncthreads();
#pragma unroll
        for (int p = 0; p < 4; p++) {
            int ocl = p * 16 + ocl2;
            int oc = nq * 128 + hf * 64 + ocl;
            float bias = ldin(upb, oc, isf32);
            f32x4 v4 = *(const f32x4*)(fl + ocl * 68 + px0);
            size_t idx = ((size_t)b * NC + oc) * HW + (size_t)row * 64 + px0;
            if (isf32) {
                f32x4 rsd = *(const f32x4*)((const float*)content + idx);
                f32x4 ov;
#pragma unroll
                for (int r = 0; r < 4; r++) ov[r] = v4[r] + bias + rsd[r];
                *(f32x4*)((float*)outv + idx) = ov;
            } else {
                ushort4 rv = *(const ushort4*)((const u16*)content + idx);
                ushort4 ov;
                ov.x = f2b(v4[0] + bias + b2f(rv.x));
                ov.y = f2b(v4[1] + bias + b2f(rv.y));
                ov.z = f2b(v4[2] + bias + b2f(rv.z));
                ov.w = f2b(v4[3] + bias + b2f(rv.w));
                *(ushort4*)((u16*)outv + idx) = ov;
            }
        }
    }
}

// ---------------------------------------------------------------------------
extern "C" void kernel_launch(void* const* d_in, const int* in_sizes, int n_in,
                              void* d_out, int out_size, void* d_ws, size_t ws_size,
                              hipStream_t stream) {
    const void* content = d_in[0];
    const void* style   = d_in[1];
    const void* ds_w    = d_in[2];
    const void* ds_b    = d_in[3];
    const void* up_w    = d_in[4];
    const void* up_b    = d_in[5];
    const void* f1_cw   = d_in[6];
    const void* f1_cb   = d_in[7];
    const void* f1_fw   = d_in[8];
    const void* f1_fb   = d_in[9];
    const void* f2_cw   = d_in[10];
    const void* f2_cb   = d_in[11];
    const void* f2_fw   = d_in[12];
    const void* f2_fb   = d_in[13];

    // Host-side dtype resolution from exact input byte sizes; -1 = unknown,
    // kernels fall back to wave-ballot bit detection.
    int hisf = -1;
    if (in_sizes && n_in >= 1) {
        if (in_sizes[0] == NB * NC * HW * 4) hisf = 1;
        else if (in_sizes[0] == NB * NC * HW * 2) hisf = 0;
    }

    const size_t SZ_PACK = 294912;       // 147456 u16
    const size_t SZ_CT2  = 2097152;      // 1,048,576 u16 (32-ch bf16 tensor)
    const size_t REQ_WS  = 3 * SZ_CT2 + 3 * SZ_PACK + 147456 * 4 + 2048 + 64;

    if (ws_size >= REQ_WS) {
        // FULL path: all intermediates in d_ws; d_out holds only cT (full
        // batch, 33,554,432 B <= out_size), dead before k_conv_up writes out.
        char* w = (char*)d_ws;
        u16*   B2pack = (u16*)w;                 w += SZ_PACK;
        u16*   c2T    = (u16*)w;                 w += SZ_CT2;
        u16*   c0T    = (u16*)w;                 w += SZ_CT2;
        u16*   c1T    = (u16*)w;                 w += SZ_CT2;
        u16*   Bpack  = (u16*)w;                 w += SZ_PACK;
        u16*   fpack  = (u16*)w;                 w += SZ_PACK;
        float* S      = (float*)w;               w += 147456 * 4;
        float* pooled = (float*)w;
        u16*   cT     = (u16*)d_out;

        // L1: style(4096) + transform(8192) + preps(2x576)
        k_front<<<4096 + 8192 + 2 * 576, 256, 0, stream>>>(
            style, S, 4096, content, cT, 0, 8192,
            ds_w, Bpack, up_w, B2pack, 576,
            pooled, f1_fw, f1_fb, f2_fw, f2_fb, fpack, hisf);
        // L2: conv_down(512) + pooled(128)
        k_mid<<<512 + 128, 256, 0, stream>>>(
            cT, Bpack, ds_b, c0T, 0, 512,
            S, f1_cw, f1_cb, f2_cw, f2_cb, pooled, content, hisf);
        // L3: fc(576)
        k_front<<<576, 256, 0, stream>>>(
            style, S, 0, content, cT, 0, 0,
            ds_w, Bpack, up_w, B2pack, 0,
            pooled, f1_fw, f1_fb, f2_fw, f2_fb, fpack, hisf);
        // L4/L5: dynamic convs
        k_apply<<<NB * 64, 256, 0, stream>>>(c0T, fpack, c1T, 1);
        k_apply<<<NB * 64, 256, 0, stream>>>(c1T, fpack + NB * 9216, c2T, 0);
        // L6: conv_up
        k_conv_up<<<dim3(NB * 64, 4), 256, 0, stream>>>(c2T, B2pack, up_b,
                                                        content, d_out, hisf);
    } else {
        // HALF path (small ws): scratch in d_out, cT half-batch reused.
        float* S      = (float*)d_out;               //    36,864 f32
        float* pooled = S + 36864;                   //       512 f32
        u16*   fpack  = (u16*)(pooled + 512);        //   147,456 u16
        u16*   Bpack  = fpack + 147456;              //   147,456 u16
        u16*   c0T    = Bpack + 147456;              // 1,048,576 u16
        u16*   c1T    = c0T + 1048576;               // 1,048,576 u16
        u16*   cTh    = c1T + 1048576;               // 8,388,608 u16
        u16*   B2pack = (u16*)d_ws;                  //   147,456 u16
        u16*   c2T    = B2pack + 147456;             // 1,048,576 u16

        // L1: style + transform(half0) + preps
        k_front<<<4096 + 4096 + 2 * 576, 256, 0, stream>>>(
            style, S, 4096, content, cTh, 0, 4096,
            ds_w, Bpack, up_w, B2pack, 576,
            pooled, f1_fw, f1_fb, f2_fw, f2_fb, fpack, hisf);
        // L2: conv_down(half0) + pooled
        k_mid<<<256 + 128, 256, 0, stream>>>(
            cTh, Bpack, ds_b, c0T, 0, 256,
            S, f1_cw, f1_cb, f2_cw, f2_cb, pooled, content, hisf);
        // L3: transform(half1) + fc
        k_front<<<4096 + 576, 256, 0, stream>>>(
            style, S, 0, content, cTh, 4, 4096,
            ds_w, Bpack, up_w, B2pack, 0,
            pooled, f1_fw, f1_fb, f2_fw, f2_fb, fpack, hisf);
        // L4: conv_down(half1)
        k_mid<<<256, 256, 0, stream>>>(
            cTh, Bpack, ds_b, c0T, 4, 256,
            S, f1_cw, f1_cb, f2_cw, f2_cb, pooled, content, hisf);
        // L5/L6: dynamic convs
        k_apply<<<NB * 64, 256, 0, stream>>>(c0T, fpack, c1T, 1);
        k_apply<<<NB * 64, 256, 0, stream>>>(c1T, fpack + NB * 9216, c2T, 0);
        // L7: conv_up
        k_conv_up<<<dim3(NB * 64, 4), 256, 0, stream>>>(c2T, B2pack, up_b,
                                                        content, d_out, hisf);
    }
}